// Round 5
// baseline (119.160 us; speedup 1.0000x reference)
//
#include <hip/hip_runtime.h>

namespace {

constexpr int   kC      = 9;
constexpr int   kH      = 80;
constexpr int   kHid    = 100;
constexpr float kNeg    = 0.1f;
constexpr int   kB      = 16;
constexpr int   kBase   = 2 * kH;        // 160 (p,x) slots per group
constexpr int   kVoxLoc = kC * kBase;    // 1440 voxels per batch group

// Histogram scheme (rounds 9-13): voxel = sum_e t*g_bin(t) depends on t only
// -> per-block count histogram over (base, t-cell): ONE ds_add_u32 per event
// (measured LDS-atomic model ~3.3 cyc/lane/instruction; count is the only
// knob -> ~9us floor for 2M events).  Stochastic cell rounding (unbiased
// Knuth dither) makes E[] the exact lerp of f(t)=t*g_bin(t) at dt=1/192
// (measured absmax 1.95e-3, threshold ~5.5e-3).
// Round 11: blocks plain-store raw histogram planes; streaming reduce sums
// them; finish does the 16x160x193x9 matmul once (no atomics anywhere).
// Round 13: per-block fields u16 -> u8 (mean 0.25 events/cell/block,
// P(count>=256) ~ 0 for this data) halves parts traffic on both sides
// (16.4 -> 8.5 MB); reduce widens u8 -> u16 exactly via even/odd-byte
// masked sums (16 planes x 255 <= 4080 < 65536).
constexpr int   kK      = 192;           // t-cells over [0,1]; nodes 0..192
constexpr int   kTPts   = (kK + 1) * kC; // 1737 MLP eval points
constexpr int   kCellsPad   = 208;       // padded cells (u8) -> 52 u32/row
constexpr int   kTPad   = kCellsPad * kC;             // 1872 T floats
constexpr int   kPWordsPerRow = kCellsPad / 4;        // 52 u32 (u8 fields)
constexpr int   kPHistWords   = kBase * kPWordsPerRow;// 8320 u32 (33,280 B)
constexpr int   kPHistUint4   = kPHistWords / 4;      // 2080
constexpr int   kGWordsPerRow = kCellsPad / 2;        // 104 u32 (u16 fields)
constexpr int   kGHistWords   = kBase * kGWordsPerRow;// 16,640 per group
constexpr int   kThreads = 1024;
constexpr int   kSubs    = 16;           // scatter blocks per group
constexpr int   kScatBlocks = kB * kSubs;             // 256
constexpr int   kPrepBlocks = (kTPts + 15) / 16;      // 109 (16 waves/block)
constexpr int   kRedThreads = kB * kPHistWords;       // 133,120

// d_ws layout: [0, 7488) T; [8192, +1.065MB) gh(u16); then 8.52MB parts(u8).
constexpr size_t kGhOff    = 8192;
constexpr size_t kPartsOff = kGhOff + (size_t)kB * kGHistWords * 4;  // 1,073,152

__device__ __forceinline__ float lrelu(float z) { return z >= 0.f ? z : kNeg * z; }

} // namespace

// Fused kernel.  Blocks [0, kScatBlocks): per-block LDS u8 count histogram
// over (base, t-cell), then raw 33KB store to parts[sub][g].  Blocks
// [kScatBlocks, +kPrepBlocks): evaluate the MLP at the 1737 (cell, bin)
// nodes, T[c*9+bin] = (c/192)*mlp(c/192 - bin/8) -- one wave per point, lane
// owns hidden col `lane` (+64+lane for lanes<36), W2 rows coalesced,
// shuffle-reduce.  Prep blocks are VALU/global-load bound, scatter blocks
// LDS-atomic bound -> separate pipes co-schedule; stream ordering guarantees
// T completes before finish_kernel launches.
__global__ __launch_bounds__(kThreads) void scatter_kernel(
    const float4* __restrict__ events,
    const float* __restrict__ W1, const float* __restrict__ b1,
    const float* __restrict__ W2, const float* __restrict__ b2,
    const float* __restrict__ W3, const float* __restrict__ b3,
    float* __restrict__ T, unsigned* __restrict__ parts, int Ngroup) {
  if (blockIdx.x >= kScatBlocks) {
    // ---- table-building path ----
    int wave = (blockIdx.x - kScatBlocks) * (kThreads >> 6) +
               ((int)threadIdx.x >> 6);
    int lane = threadIdx.x & 63;
    if (wave == 0) {  // zero the 135 pad floats (NaN-poison guard)
      for (int k = lane; k < kTPad - kTPts; k += 64) T[kTPts + k] = 0.f;
    }
    if (wave >= kTPts) return;

    int c   = wave / kC;
    int bin = wave - kC * c;                 // wave = c*9 + bin
    float tc = (float)c * (1.0f / (float)kK);
    float ts = tc - 0.125f * (float)bin;     // t - bin/(C-1)

    bool two = (lane < kHid - 64);
    float acc1 = 0.f, acc2 = 0.f;
    for (int j = 0; j < kHid; ++j) {
      float h1 = lrelu(fmaf(ts, W1[j], b1[j]));
      const float* row = W2 + j * kHid;
      acc1 = fmaf(h1, row[lane], acc1);
      float w2b = two ? row[64 + lane] : 0.f;
      acc2 = fmaf(h1, w2b, acc2);
    }
    float o = lrelu(acc1 + b2[lane]) * W3[lane];
    if (two) o += lrelu(acc2 + b2[64 + lane]) * W3[64 + lane];
#pragma unroll
    for (int off = 32; off >= 1; off >>= 1) o += __shfl_xor(o, off);
    if (lane == 0) T[wave] = tc * (o + b3[0]);
    return;
  }

  // ---- scatter path ----
  __shared__ unsigned s_hist[kPHistWords] __attribute__((aligned(16)));
  uint4* s4 = reinterpret_cast<uint4*>(s_hist);
  uint4 z4 = make_uint4(0u, 0u, 0u, 0u);
  for (int i = threadIdx.x; i < kPHistUint4; i += kThreads) s4[i] = z4;
  __syncthreads();

  int g   = blockIdx.x / kSubs;
  int sub = blockIdx.x % kSubs;
  int per = (Ngroup + kSubs - 1) / kSubs;
  int start = g * Ngroup + sub * per;
  int end   = g * Ngroup + min((sub + 1) * per, Ngroup);

  for (int i = start + (int)threadIdx.x; i < end; i += kThreads) {
    float4 e = events[i];                       // (x, t, p, b)
    int base = (int)e.z * kH + (int)e.x - 1;    // p*80 + (x-1), in [0,160)
    base = min(max(base, 0), kBase - 1);        // LDS OOB guard
    // per-event dither in [0,1): Knuth hash of event index; c =
    // floor(t*192 + dith) is unbiased stochastic rounding -> E = lerp.
    float dith = (float)((unsigned)i * 2654435761u >> 8) * (1.0f / 16777216.0f);
    int c = (int)fmaf(e.y, (float)kK, dith);    // in [0, 192]
    c = min(max(c, 0), kK);                     // defensive
    // u8 field c&3 of word c>>2 (mean 0.25 events/cell/block -> no overflow)
    atomicAdd(&s_hist[base * kPWordsPerRow + (c >> 2)], 1u << ((c & 3) << 3));
  }
  __syncthreads();

  uint4* dst = reinterpret_cast<uint4*>(parts) +
               (size_t)(sub * kB + g) * kPHistUint4;
  for (int i = threadIdx.x; i < kPHistUint4; i += kThreads) dst[i] = s4[i];
}

// Widening reduce: each thread owns one parts u32 (4 u8 cells) per group,
// sums 16 sub-planes with even/odd-byte masks (exact: 16*255 = 4080 < 2^16)
// and stores 2 u32 of u16-packed gh.  Reads 8.5 MB coalesced, writes 1.06MB.
__global__ __launch_bounds__(256) void reduce_kernel(
    const unsigned* __restrict__ parts, unsigned* __restrict__ gh) {
  int j = blockIdx.x * 256 + (int)threadIdx.x;   // (g, row, q) flattened
  if (j >= kRedThreads) return;
  unsigned s02 = 0u, s13 = 0u;
#pragma unroll
  for (int s = 0; s < kSubs; ++s) {
    unsigned v = parts[(size_t)s * kRedThreads + j];
    s02 += v & 0x00FF00FFu;
    s13 += (v >> 8) & 0x00FF00FFu;
  }
  int g = j / kPHistWords;
  int r = j - g * kPHistWords;                   // row*52 + q
  int row = r / kPWordsPerRow;
  int q   = r - row * kPWordsPerRow;
  unsigned* dst = gh + (size_t)g * kGHistWords + row * kGWordsPerRow + 2 * q;
  dst[0] = (s02 & 0xFFFFu) | ((s13 & 0xFFFFu) << 16);          // cells 4q,4q+1
  dst[1] = (s02 >> 16) | (s13 & 0xFFFF0000u);                  // cells 4q+2,4q+3
}

// One thread per output voxel: out[g][bin][base] = 0.01 * sum_c
// hist[g][base][c] * T[c*9+bin].  9 consecutive lanes share a hist row
// (broadcast uint4 loads, L2-resident) and read 9 consecutive T floats
// (L1-resident 7.5 KB).  Plain store -> no init, no atomics.
__global__ __launch_bounds__(128) void finish_kernel(
    const unsigned* __restrict__ ghist, const float* __restrict__ T,
    float* __restrict__ out) {
  int tid = blockIdx.x * 128 + (int)threadIdx.x;
  if (tid >= kB * kVoxLoc) return;
  int g = tid / kVoxLoc;
  int r = tid - g * kVoxLoc;
  int base = r / kC;
  int bin  = r - kC * base;
  const uint4* row = reinterpret_cast<const uint4*>(
      ghist + (size_t)g * kGHistWords + base * kGWordsPerRow);
  const float* Tb = T + bin;
  float acc = 0.f;
#pragma unroll 13
  for (int q = 0; q < kGWordsPerRow / 4; ++q) {   // 26 x uint4 (208 cells)
    uint4 w = row[q];
    int c0 = q * 8;
    acc = fmaf((float)(w.x & 0xFFFFu), Tb[(c0 + 0) * kC], acc);
    acc = fmaf((float)(w.x >> 16),     Tb[(c0 + 1) * kC], acc);
    acc = fmaf((float)(w.y & 0xFFFFu), Tb[(c0 + 2) * kC], acc);
    acc = fmaf((float)(w.y >> 16),     Tb[(c0 + 3) * kC], acc);
    acc = fmaf((float)(w.z & 0xFFFFu), Tb[(c0 + 4) * kC], acc);
    acc = fmaf((float)(w.z >> 16),     Tb[(c0 + 5) * kC], acc);
    acc = fmaf((float)(w.w & 0xFFFFu), Tb[(c0 + 6) * kC], acc);
    acc = fmaf((float)(w.w >> 16),     Tb[(c0 + 7) * kC], acc);
  }
  out[g * kVoxLoc + bin * kBase + base] = acc * 0.01f;
}

extern "C" void kernel_launch(void* const* d_in, const int* in_sizes, int n_in,
                              void* d_out, int out_size, void* d_ws, size_t ws_size,
                              hipStream_t stream) {
  const float4* events = (const float4*)d_in[0];
  const float* W1 = (const float*)d_in[1];
  const float* b1 = (const float*)d_in[2];
  const float* W2 = (const float*)d_in[3];
  const float* b2 = (const float*)d_in[4];
  const float* W3 = (const float*)d_in[5];
  const float* b3 = (const float*)d_in[6];
  float* out = (float*)d_out;
  float* T = (float*)d_ws;                                    // 7.49 KB
  unsigned* gh    = (unsigned*)((char*)d_ws + kGhOff);        // 1.065 MB
  unsigned* parts = (unsigned*)((char*)d_ws + kPartsOff);     // 8.52 MB

  int N = in_sizes[0] / 4;
  int Ngroup = N / kB;

  scatter_kernel<<<kScatBlocks + kPrepBlocks, kThreads, 0, stream>>>(
      events, W1, b1, W2, b2, W3, b3, T, parts, Ngroup);
  reduce_kernel<<<(kRedThreads + 255) / 256, 256, 0, stream>>>(
      parts, gh);
  finish_kernel<<<(kB * kVoxLoc + 127) / 128, 128, 0, stream>>>(
      gh, T, out);
}

// Round 6
// 102.766 us; speedup vs baseline: 1.1595x; 1.1595x over previous
//
#include <hip/hip_runtime.h>

namespace {

constexpr int   kC      = 9;
constexpr int   kH      = 80;
constexpr int   kHid    = 100;
constexpr float kNeg    = 0.1f;
constexpr int   kB      = 16;
constexpr int   kBase   = 2 * kH;        // 160 (p,x) slots per group
constexpr int   kVoxLoc = kC * kBase;    // 1440 voxels per batch group

// Histogram scheme (rounds 9-14): voxel = sum_e t*g_bin(t) depends on t only
// -> per-block u16 count histogram over (base, t-cell): ONE ds_add_u32 per
// event (measured LDS-atomic model: ~3.3 cyc/lane/instruction, count is the
// only knob).  Stochastic cell rounding (unbiased Knuth dither) makes E[]
// the exact lerp of f(t) = t*g_bin(t) at dt = 1/192 (measured absmax
// 1.95e-3, threshold ~5.5e-3).
// Round 11: counts are additive -> blocks plain-store raw 64KB histograms to
// private parts[sub] planes (coalesced, no init), reduce sums 16 planes
// (streaming BW), finish does the 16x160x193x9 matmul once w/ plain stores.
// Measured 101.0us.  Round 13 (u8 fields) measured 119.2us (+18) with no
// constructible mechanism (all traffic shrank; fills themselves slowed 43->46
// on a different container) -> round 14 reverts verbatim to the 101.0us
// kernel as a drift A/B: ~101 => u8 was real, continue; ~119 => drift,
// controllable region at its floor (atomic ~9us + event stream 5.1us).
constexpr int   kK      = 192;           // t-cells over [0,1]; nodes 0..192
constexpr int   kTPts   = (kK + 1) * kC; // 1737 MLP eval points
constexpr int   kTPad   = 1800;          // T floats incl. pad (uint4 tail)
constexpr int   kWordsPerRow = 100;      // 200 u16 cells = 100 u32 (400 B)
constexpr int   kHistWords   = kBase * kWordsPerRow;  // 16000 u32 (64 KB)
constexpr int   kHistUint4   = kHistWords / 4;        // 4000
constexpr int   kThreads = 1024;
constexpr int   kSubs    = 16;           // scatter blocks per group
constexpr int   kScatBlocks = kB * kSubs;             // 256
constexpr int   kPrepBlocks = (kTPts + 15) / 16;      // 109 (16 waves/block)
constexpr int   kRedUint4   = kB * kHistUint4;        // 64000

// d_ws layout: [0, 7200) T; [8192, +1MB) gh; then 16 MB parts.
constexpr size_t kGhOff    = 8192;
constexpr size_t kPartsOff = kGhOff + (size_t)kB * kHistWords * 4;  // 1032192

__device__ __forceinline__ float lrelu(float z) { return z >= 0.f ? z : kNeg * z; }

} // namespace

// Fused kernel.  Blocks [0, kScatBlocks): per-block LDS count histogram over
// (base, t-cell), then raw 64KB store to parts[sub][g].  Blocks
// [kScatBlocks, +kPrepBlocks): evaluate the MLP at the 1737 (cell, bin)
// nodes, T[c*9+bin] = (c/192)*mlp(c/192 - bin/8) -- one wave per point, lane
// owns hidden col `lane` (+64+lane for lanes<36), W2 rows coalesced,
// shuffle-reduce.  Prep blocks are VALU/global-load bound, scatter blocks
// LDS-atomic bound -> separate pipes co-schedule; stream ordering guarantees
// T completes before finish_kernel launches.
__global__ __launch_bounds__(kThreads) void scatter_kernel(
    const float4* __restrict__ events,
    const float* __restrict__ W1, const float* __restrict__ b1,
    const float* __restrict__ W2, const float* __restrict__ b2,
    const float* __restrict__ W3, const float* __restrict__ b3,
    float* __restrict__ T, unsigned* __restrict__ parts, int Ngroup) {
  if (blockIdx.x >= kScatBlocks) {
    // ---- table-building path ----
    int wave = (blockIdx.x - kScatBlocks) * (kThreads >> 6) +
               ((int)threadIdx.x >> 6);
    int lane = threadIdx.x & 63;
    if (wave == 0 && lane < kTPad - kTPts)   // zero 63 pad floats (poison!)
      T[kTPts + lane] = 0.f;
    if (wave >= kTPts) return;

    int c   = wave / kC;
    int bin = wave - kC * c;                 // wave = c*9 + bin
    float tc = (float)c * (1.0f / (float)kK);
    float ts = tc - 0.125f * (float)bin;     // t - bin/(C-1)

    bool two = (lane < kHid - 64);
    float acc1 = 0.f, acc2 = 0.f;
    for (int j = 0; j < kHid; ++j) {
      float h1 = lrelu(fmaf(ts, W1[j], b1[j]));
      const float* row = W2 + j * kHid;
      acc1 = fmaf(h1, row[lane], acc1);
      float w2b = two ? row[64 + lane] : 0.f;
      acc2 = fmaf(h1, w2b, acc2);
    }
    float o = lrelu(acc1 + b2[lane]) * W3[lane];
    if (two) o += lrelu(acc2 + b2[64 + lane]) * W3[64 + lane];
#pragma unroll
    for (int off = 32; off >= 1; off >>= 1) o += __shfl_xor(o, off);
    if (lane == 0) T[wave] = tc * (o + b3[0]);
    return;
  }

  // ---- scatter path ----
  __shared__ unsigned s_hist[kHistWords] __attribute__((aligned(16)));
  uint4* s4 = reinterpret_cast<uint4*>(s_hist);
  uint4 z4 = make_uint4(0u, 0u, 0u, 0u);
  for (int i = threadIdx.x; i < kHistUint4; i += kThreads) s4[i] = z4;
  __syncthreads();

  int g   = blockIdx.x / kSubs;
  int sub = blockIdx.x % kSubs;
  int per = (Ngroup + kSubs - 1) / kSubs;
  int start = g * Ngroup + sub * per;
  int end   = g * Ngroup + min((sub + 1) * per, Ngroup);

  for (int i = start + (int)threadIdx.x; i < end; i += kThreads) {
    float4 e = events[i];                       // (x, t, p, b)
    int base = (int)e.z * kH + (int)e.x - 1;    // p*80 + (x-1), in [0,160)
    base = min(max(base, 0), kBase - 1);        // LDS OOB guard
    // per-event dither in [0,1): Knuth hash of event index; c =
    // floor(t*192 + dith) is unbiased stochastic rounding -> E = lerp.
    float dith = (float)((unsigned)i * 2654435761u >> 8) * (1.0f / 16777216.0f);
    int c = (int)fmaf(e.y, (float)kK, dith);    // in [0, 192]
    c = min(max(c, 0), kK);                     // defensive
    atomicAdd(&s_hist[base * kWordsPerRow + (c >> 1)], 1u << ((c & 1) << 4));
  }
  __syncthreads();

  uint4* dst = reinterpret_cast<uint4*>(parts) +
               (size_t)sub * (kB * kHistUint4) + g * kHistUint4;
  for (int i = threadIdx.x; i < kHistUint4; i += kThreads) dst[i] = s4[i];
}

// gh[j] = sum over 16 sub-planes (uint4 lanes, perfectly coalesced reads of
// 16 MB, plain 1 MB store).  u16 fields exact: per-(group,base,cell) counts
// are ~Poisson(4) -- nowhere near 65535.
__global__ __launch_bounds__(256) void reduce_kernel(
    const uint4* __restrict__ parts, uint4* __restrict__ gh) {
  int j = blockIdx.x * 256 + (int)threadIdx.x;
  if (j >= kRedUint4) return;
  uint4 a = make_uint4(0u, 0u, 0u, 0u);
#pragma unroll
  for (int s = 0; s < kSubs; ++s) {
    uint4 v = parts[(size_t)s * kRedUint4 + j];
    a.x += v.x; a.y += v.y; a.z += v.z; a.w += v.w;
  }
  gh[j] = a;
}

// One thread per output voxel: out[g][bin][base] = 0.01 * sum_c
// hist[g][base][c] * T[c*9+bin].  9 consecutive lanes share a hist row
// (broadcast uint4 loads, L2-resident 1 MB read 9x) and read 9 consecutive
// T floats (L1-resident 7.2 KB).  Plain store -> no init, no atomics.
// 128-thread blocks -> 180 blocks (round-10's 90 left CUs idle).
__global__ __launch_bounds__(128) void finish_kernel(
    const unsigned* __restrict__ ghist, const float* __restrict__ T,
    float* __restrict__ out) {
  int tid = blockIdx.x * 128 + (int)threadIdx.x;
  if (tid >= kB * kVoxLoc) return;
  int g = tid / kVoxLoc;
  int r = tid - g * kVoxLoc;
  int base = r / kC;
  int bin  = r - kC * base;
  const uint4* row = reinterpret_cast<const uint4*>(
      ghist + g * kHistWords + base * kWordsPerRow);
  const float* Tb = T + bin;
  float acc = 0.f;
#pragma unroll 5
  for (int q = 0; q < kWordsPerRow / 4; ++q) {   // 25 x uint4
    uint4 w = row[q];
    int c0 = q * 8;
    acc = fmaf((float)(w.x & 0xFFFFu), Tb[(c0 + 0) * kC], acc);
    acc = fmaf((float)(w.x >> 16),     Tb[(c0 + 1) * kC], acc);
    acc = fmaf((float)(w.y & 0xFFFFu), Tb[(c0 + 2) * kC], acc);
    acc = fmaf((float)(w.y >> 16),     Tb[(c0 + 3) * kC], acc);
    acc = fmaf((float)(w.z & 0xFFFFu), Tb[(c0 + 4) * kC], acc);
    acc = fmaf((float)(w.z >> 16),     Tb[(c0 + 5) * kC], acc);
    acc = fmaf((float)(w.w & 0xFFFFu), Tb[(c0 + 6) * kC], acc);
    acc = fmaf((float)(w.w >> 16),     Tb[(c0 + 7) * kC], acc);
  }
  out[g * kVoxLoc + bin * kBase + base] = acc * 0.01f;
}

extern "C" void kernel_launch(void* const* d_in, const int* in_sizes, int n_in,
                              void* d_out, int out_size, void* d_ws, size_t ws_size,
                              hipStream_t stream) {
  const float4* events = (const float4*)d_in[0];
  const float* W1 = (const float*)d_in[1];
  const float* b1 = (const float*)d_in[2];
  const float* W2 = (const float*)d_in[3];
  const float* b2 = (const float*)d_in[4];
  const float* W3 = (const float*)d_in[5];
  const float* b3 = (const float*)d_in[6];
  float* out = (float*)d_out;
  float* T = (float*)d_ws;                                    // 7.2 KB
  unsigned* gh    = (unsigned*)((char*)d_ws + kGhOff);        // 1.024 MB
  unsigned* parts = (unsigned*)((char*)d_ws + kPartsOff);     // 16.384 MB

  int N = in_sizes[0] / 4;
  int Ngroup = N / kB;

  scatter_kernel<<<kScatBlocks + kPrepBlocks, kThreads, 0, stream>>>(
      events, W1, b1, W2, b2, W3, b3, T, parts, Ngroup);
  reduce_kernel<<<(kRedUint4 + 255) / 256, 256, 0, stream>>>(
      (const uint4*)parts, (uint4*)gh);
  finish_kernel<<<(kB * kVoxLoc + 127) / 128, 128, 0, stream>>>(
      gh, T, out);
}